// Round 13
// baseline (78.909 us; speedup 1.0000x reference)
//
#include <hip/hip_runtime.h>

#define F 64
#define SECAP 8192
#define TCAP 2048
#define FCAP 8256
#define BLK 256
#define EPIW 4   // waves per kp_epi block
#define FLAGMAGIC 0x13579BDFull

struct Params {
  const float *x, *ew, *f0w, *f0b, *f1w, *f1b, *cw, *cb;
  const int *pos, *esrc, *edst;
  float *out;
  int B, E;
  int *cnt;            // [0]=SE count, [2]=frontier count
  int *TEn;            // per-output-slot TE counts (B)
  unsigned *bitmap;    // frontier membership, (N+31)/32 words
  int *sel, *slotb, *slot_of, *SEb, *SEd, *TEsrc2;
  float *SEw, *TEw2, *AGG, *wsum, *zf;
  float *P0, *G, *V, *Wp;          // 64x64 weight products
  float *b0c, *gb, *vb, *wpb;      // 64-vec products
  int *zwords;                     // zero region (cnt..bitmap), word count nzw
  int nzw;
  unsigned *gen;                   // per-call generation (epi increments)
  unsigned long long *flag;        // zero-done flag: (MAGIC<<32)|gen
};

// broadcast matvec: res = init + sum_f vec[f]*mat[f*64+h]; vec in LDS (float4 reads)
#define MVB(res, init, vecp, mat)                         \
  {                                                       \
    float a0_ = 0.f, a1_ = 0.f, a2_ = 0.f, a3_ = 0.f;     \
    _Pragma("unroll")                                     \
    for (int q_ = 0; q_ < 16; ++q_) {                     \
      float4 vv_ = ((const float4*)(vecp))[q_];           \
      a0_ += vv_.x * (mat)[(4 * q_ + 0) * 64 + h];        \
      a1_ += vv_.y * (mat)[(4 * q_ + 1) * 64 + h];        \
      a2_ += vv_.z * (mat)[(4 * q_ + 2) * 64 + h];        \
      a3_ += vv_.w * (mat)[(4 * q_ + 3) * 64 + h];        \
    }                                                     \
    res = (init) + ((a0_ + a1_) + (a2_ + a3_));           \
  }

// mark node n; first marker assigns a compact slot and zeroes its AGG row+wsum
__device__ __forceinline__ void mark_assign(const Params& p, int n) {
  unsigned bit = 1u << (n & 31);
  unsigned old = atomicOr(&p.bitmap[n >> 5], bit);
  if (!(old & bit)) {
    int sl = atomicAdd(&p.cnt[2], 1);
    if (sl < FCAP) {
      p.slot_of[n] = sl;
      float4* row = (float4*)(p.AGG + (size_t)sl * F);
#pragma unroll
      for (int k = 0; k < 16; ++k) row[k] = make_float4(0.f, 0.f, 0.f, 0.f);
      p.wsum[sl] = 0.f;
    } else {
      p.slot_of[n] = 0;   // pathological overflow guard
    }
  }
}

// ---- K1: blocks [0,nbE): edge scan. Block 0 zeroes {cnt,TEn,bitmap} then
// ----     publishes a generation-tagged flag; other blocks spin (all blocks
// ----     co-resident: <=2053 blocks, 4 waves each, nothing else running).
// ----     Blocks [nbE, nbE+5): weight products (no counter dependency).
__global__ __launch_bounds__(BLK) void kp_scan(Params p, int nbE) {
  const int tid = threadIdx.x;
  if ((int)blockIdx.x >= nbE) {
    // ---------- weight-product blocks ----------
    __shared__ __align__(16) float Al[64][64];
    const int ty = tid >> 6, h = tid & 63;
    int wb = blockIdx.x - nbE;
    if (wb < 4) {
      const float *A, *A2 = nullptr, *Bm;
      float* Om;
      if (wb == 0)      { A = p.f0w;        Bm = p.cw;        Om = p.P0; }
      else if (wb == 1) { A = p.f1w;        A2 = p.f0w; Bm = p.cw; Om = p.G; }
      else if (wb == 2) { A = p.f1w + 4096; Bm = p.cw + 4096; Om = p.V; }
      else              { A = p.f0w + 4096; Bm = p.cw + 4096; Om = p.Wp; }
      for (int i = tid; i < 4096; i += BLK)
        Al[i >> 6][i & 63] = A2 ? (A[i] - A2[i]) : A[i];
      __syncthreads();
      float acc[16];
#pragma unroll
      for (int fi = 0; fi < 16; ++fi) acc[fi] = 0.f;
      for (int k = 0; k < 64; ++k) {
        float bkh = Bm[k * 64 + h];
#pragma unroll
        for (int fi = 0; fi < 16; ++fi)
          acc[fi] += Al[ty * 16 + fi][k] * bkh;
      }
#pragma unroll
      for (int fi = 0; fi < 16; ++fi)
        Om[(ty * 16 + fi) * 64 + h] = acc[fi];
    } else {
      const float *vsrc, *v2 = nullptr, *Bm;
      float* Ov;
      if (ty == 0)      { vsrc = p.f0b;      Bm = p.cw;        Ov = p.b0c; }
      else if (ty == 1) { vsrc = p.f1b;      v2 = p.f0b; Bm = p.cw; Ov = p.gb; }
      else if (ty == 2) { vsrc = p.f1b + 64; Bm = p.cw + 4096; Ov = p.vb; }
      else              { vsrc = p.f0b + 64; Bm = p.cw + 4096; Ov = p.wpb; }
      Al[ty][h] = v2 ? (vsrc[h] - v2[h]) : vsrc[h];   // same-wave LDS RAW
      float acc;
      MVB(acc, 0.f, Al[ty], Bm);
      Ov[h] = acc;
    }
    return;
  }
  // ---------- zero-gate: block 0 zeroes, others spin on tagged flag ----------
  // gen is stable during this node (only kp_epi, a later node, increments it).
  unsigned g = __hip_atomic_load(p.gen, __ATOMIC_RELAXED, __HIP_MEMORY_SCOPE_AGENT);
  unsigned long long expected = (FLAGMAGIC << 32) | (unsigned long long)g;
  if (blockIdx.x == 0) {
    for (int i = tid; i < p.nzw; i += BLK) p.zwords[i] = 0;
    __threadfence();                 // make zeroes agent-visible
    __syncthreads();                 // all zero-stores done before flag
    if (tid == 0)
      __hip_atomic_store(p.flag, expected, __ATOMIC_RELEASE, __HIP_MEMORY_SCOPE_AGENT);
  } else {
    if (tid == 0) {
      while (__hip_atomic_load(p.flag, __ATOMIC_ACQUIRE, __HIP_MEMORY_SCOPE_AGENT)
             != expected) {}
    }
    __syncthreads();                 // gate whole block on the spin
  }
  // ---------- edge scan: 1 edge/thread, grid-stride ----------
  __shared__ int posL[16], rankL[16];
  const int B = p.B;
  if (tid < B) {
    int v = p.pos[tid];
    int rank = 0;
    for (int j = 0; j < B; ++j) rank += (p.pos[j] < v);
    posL[tid] = v;
    rankL[tid] = rank;
  }
  __syncthreads();
  if (blockIdx.x == 0 && tid < B) {
    p.sel[rankL[tid]] = posL[tid];      // unique ascending (values distinct)
    p.slotb[tid] = rankL[tid ^ 1];      // batch = rank of partner node
    mark_assign(p, posL[tid]);          // seed frontier with labeled nodes
  }
  int gtid = blockIdx.x * BLK + tid;
  int nthr = nbE * BLK;
  for (int e = gtid; e < p.E; e += nthr) {
    int s = p.esrc[e], d = p.edst[e];
    float w = p.ew[e];
    int bi = -1, ti = -1;
#pragma unroll
    for (int j = 0; j < 16; ++j) {
      if (j < B) {
        if (s == posL[j]) bi = rankL[j];
        if (d == posL[j]) ti = j;
      }
    }
    if (bi >= 0) {                      // src is labeled: SE entry
      int idx = atomicAdd(&p.cnt[0], 1);
      if (idx < SECAP) { p.SEb[idx] = bi; p.SEd[idx] = d; p.SEw[idx] = w; }
    }
    if (ti >= 0) {                      // dst is a target: bucket + mark src
      int idx = atomicAdd(&p.TEn[ti], 1);
      if (idx < TCAP) { p.TEsrc2[ti * TCAP + idx] = s; p.TEw2[ti * TCAP + idx] = w; }
      mark_assign(p, s);
    }
  }
}

// ---- K2: AGG_x[slot(d)] += w * x[src] over edges into frontier nodes ----
__global__ __launch_bounds__(BLK) void kp_agg(Params p) {
  int gtid = blockIdx.x * BLK + threadIdx.x;
  int nthr = gridDim.x * BLK;
  for (int e = gtid; e < p.E; e += nthr) {
    int d = p.edst[e];
    if (!((p.bitmap[d >> 5] >> (d & 31)) & 1u)) continue;
    int sl = p.slot_of[d];
    if ((unsigned)sl >= (unsigned)FCAP) continue;
    int s = p.esrc[e];
    float w = p.ew[e];
    const float4* xs = (const float4*)(p.x + (size_t)s * F);
    float* dst = p.AGG + (size_t)sl * F;
#pragma unroll
    for (int k = 0; k < 16; ++k) {
      float4 v = xs[k];
      atomicAdd(dst + 4 * k + 0, w * v.x);
      atomicAdd(dst + 4 * k + 1, w * v.y);
      atomicAdd(dst + 4 * k + 2, w * v.z);
      atomicAdd(dst + 4 * k + 3, w * v.w);
    }
    atomicAdd(&p.wsum[sl], w);
  }
}

// ---- K3: zf[slot] = AGG@P0 + wsum*b0c + cb0  (single MVB per slot) ----
__global__ __launch_bounds__(BLK) void kp_zf(Params p) {
  __shared__ __align__(16) float a[4][64];
  const int Fn = min(p.cnt[2], FCAP);
  const int ty = threadIdx.x >> 6, h = threadIdx.x & 63;
  for (int sl = blockIdx.x * 4 + ty; sl < Fn; sl += gridDim.x * 4) {
    a[ty][h] = p.AGG[(size_t)sl * F + h];   // same-wave in-order LDS RAW
    float z;
    MVB(z, p.wsum[sl] * p.b0c[h] + p.cb[h], a[ty], p.P0);
    p.zf[(size_t)sl * F + h] = z;
  }
}

// ---- K4: epilogue. One block (4 waves) per output slot; 3 serial MVBs.
// ----     Block 0 thread 0 bumps the generation at the very end.
__global__ __launch_bounds__(BLK) void kp_epi(Params p) {
  __shared__ float cL[FCAP];            // c_{b,slot} for this block's batch b
  __shared__ __align__(16) float v0[EPIW][64];
  __shared__ __align__(16) float Sp[EPIW][64];
  __shared__ float wnsL[EPIW], wselL[EPIW];
  __shared__ int slL[TCAP];
  __shared__ float twL[TCAP];
  const int t = blockIdx.x;
  const int tid = threadIdx.x;
  const int h = tid & 63, wv = tid >> 6;
  const int b = p.slotb[t];
  const int seln = p.sel[b];            // labeled node of batch b
  const int Fn = min(p.cnt[2], FCAP);
  for (int i = tid; i < Fn; i += BLK) cL[i] = 0.f;
  __syncthreads();
  // build c-row: SE entries of batch b landing on frontier nodes (LDS atomics)
  int sen = min(p.cnt[0], SECAP);
  for (int i = tid; i < sen; i += BLK) {
    if (p.SEb[i] == b) {
      int d = p.SEd[i];
      if ((p.bitmap[d >> 5] >> (d & 31)) & 1u) {
        int sl = p.slot_of[d];
        if ((unsigned)sl < (unsigned)FCAP) atomicAdd(&cL[sl], p.SEw[i]);
      }
    }
  }
  // stage TE bucket: slot (or -1 for labeled-src) + weight
  int ten = min(p.TEn[t], TCAP);
  for (int i = tid; i < ten; i += BLK) {
    int s = p.TEsrc2[t * TCAP + i];
    int sl;
    if (s == seln) sl = -1;
    else { sl = p.slot_of[s]; if ((unsigned)sl >= (unsigned)FCAP) sl = 0; }
    slL[i] = sl;
    twL[i] = p.TEw2[t * TCAP + i];
  }
  __syncthreads();
  // ---- per-wave: g0 = x[seln]@G + gb (1 MVB) ----
  v0[wv][h] = p.x[(size_t)seln * F + h];
  float g0h;
  MVB(g0h, p.gb[h], v0[wv], p.G);
  // h1self = relu(zf[sslot] + c_self*g0); x11T = h1self@V + vb (1 MVB)
  int sslot = p.slot_of[seln];
  if ((unsigned)sslot >= (unsigned)FCAP) sslot = 0;
  float h1self = fmaxf(p.zf[(size_t)sslot * F + h] + cL[sslot] * g0h, 0.f);
  v0[wv][h] = h1self;
  float x11Th;
  MVB(x11Th, p.vb[h], v0[wv], p.V);
  // ---- wave-split TE edge loop: one zf row load + FMA per entry ----
  float S = 0.f, wns = 0.f, wsel = 0.f;
  for (int i = wv; i < ten; i += EPIW) {
    int sl = slL[i];
    float w = twL[i];
    if (sl < 0) { wsel += w; continue; }
    float h1 = fmaxf(p.zf[(size_t)sl * F + h] + cL[sl] * g0h, 0.f);
    S += w * h1;
    wns += w;
  }
  Sp[wv][h] = S;
  if (h == 0) { wnsL[wv] = wns; wselL[wv] = wsel; }
  __syncthreads();
  // ---- wave 0: combine, out = S@Wp + wns*wpb + wsel*x11T + cb1 (1 MVB) ----
  if (wv == 0) {
    float Sh = Sp[0][h] + Sp[1][h] + Sp[2][h] + Sp[3][h];
    float wnsT = wnsL[0] + wnsL[1] + wnsL[2] + wnsL[3];
    float wselT = wselL[0] + wselL[1] + wselL[2] + wselL[3];
    v0[0][h] = Sh;
    float o;
    MVB(o, wnsT * p.wpb[h] + wselT * x11Th + p.cb[64 + h], v0[0], p.Wp);
    p.out[t * F + h] = o;
  }
  // bump generation for the next call (gen is read only by earlier nodes)
  if (t == 0 && tid == 0) {
    unsigned g = __hip_atomic_load(p.gen, __ATOMIC_RELAXED, __HIP_MEMORY_SCOPE_AGENT);
    __hip_atomic_store(p.gen, g + 1u, __ATOMIC_RELEASE, __HIP_MEMORY_SCOPE_AGENT);
  }
}

extern "C" void kernel_launch(void* const* d_in, const int* in_sizes, int n_in,
                              void* d_out, int out_size, void* d_ws, size_t ws_size,
                              hipStream_t stream) {
  Params hp;
  hp.x = (const float*)d_in[0];
  hp.pos = (const int*)d_in[1];
  hp.esrc = (const int*)d_in[2];
  hp.edst = (const int*)d_in[3];
  hp.ew = (const float*)d_in[4];
  hp.f0w = (const float*)d_in[5];
  hp.f0b = (const float*)d_in[6];
  hp.f1w = (const float*)d_in[7];
  hp.f1b = (const float*)d_in[8];
  hp.cw = (const float*)d_in[9];
  hp.cb = (const float*)d_in[10];
  hp.out = (float*)d_out;
  const int N = in_sizes[0] / F;   // 10000
  hp.B = in_sizes[1];              // 16
  hp.E = in_sizes[2];              // 160000

  char* w = (char*)d_ws;
  size_t off = 0;
  auto take = [&](size_t nb) { size_t r = off; off += (nb + 255) & ~(size_t)255; return r; };
  // ---- region zeroed by kp_scan block 0 (contiguous from 0): cnt, TEn, bitmap ----
  size_t o_cnt = take(256);
  size_t o_ten = take(256);
  size_t o_bitmap = take(((size_t)N + 31) / 32 * 4);
  size_t zero_end = off;
  // ---- gen/flag (never zeroed; gen-tag protocol handles poison) ----
  size_t o_gen = take(256);
  // ---- not zeroed (lazily initialized / fully overwritten before read) ----
  size_t o_sel = take(256);
  size_t o_slotb = take(256);
  size_t o_slotof = take((size_t)N * 4);
  size_t o_seb = take(SECAP * 4);
  size_t o_sed = take(SECAP * 4);
  size_t o_sew = take(SECAP * 4);
  size_t o_tesrc = take((size_t)hp.B * TCAP * 4);
  size_t o_tew = take((size_t)hp.B * TCAP * 4);
  size_t o_agg = take((size_t)FCAP * F * 4);
  size_t o_wsum = take((size_t)FCAP * 4);
  size_t o_zf = take((size_t)FCAP * F * 4);
  size_t o_P0 = take(4096 * 4);
  size_t o_G = take(4096 * 4);
  size_t o_V = take(4096 * 4);
  size_t o_Wp = take(4096 * 4);
  size_t o_b0c = take(256);
  size_t o_gb = take(256);
  size_t o_vb = take(256);
  size_t o_wpb = take(256);
  (void)ws_size;                   // ~5.8 MB total; ws is far larger

  hp.cnt = (int*)(w + o_cnt);
  hp.TEn = (int*)(w + o_ten);
  hp.bitmap = (unsigned*)(w + o_bitmap);
  hp.gen = (unsigned*)(w + o_gen);
  hp.flag = (unsigned long long*)(w + o_gen + 8);
  hp.sel = (int*)(w + o_sel);
  hp.slotb = (int*)(w + o_slotb);
  hp.slot_of = (int*)(w + o_slotof);
  hp.SEb = (int*)(w + o_seb);
  hp.SEd = (int*)(w + o_sed);
  hp.SEw = (float*)(w + o_sew);
  hp.TEsrc2 = (int*)(w + o_tesrc);
  hp.TEw2 = (float*)(w + o_tew);
  hp.AGG = (float*)(w + o_agg);
  hp.wsum = (float*)(w + o_wsum);
  hp.zf = (float*)(w + o_zf);
  hp.P0 = (float*)(w + o_P0);
  hp.G = (float*)(w + o_G);
  hp.V = (float*)(w + o_V);
  hp.Wp = (float*)(w + o_Wp);
  hp.b0c = (float*)(w + o_b0c);
  hp.gb = (float*)(w + o_gb);
  hp.vb = (float*)(w + o_vb);
  hp.wpb = (float*)(w + o_wpb);
  hp.zwords = (int*)w;
  hp.nzw = (int)(zero_end / 4);

  // node 1: edge scan (zero-gate inside) + weight-product blocks
  int nbE = (hp.E + BLK - 1) / BLK;
  if (nbE > 2048) nbE = 2048;      // keep all blocks co-resident (spin safety)
  kp_scan<<<nbE + 5, BLK, 0, stream>>>(hp, nbE);
  // node 2: frontier aggregation
  kp_agg<<<nbE, BLK, 0, stream>>>(hp);
  // node 3: zf transform, parallel over frontier slots
  kp_zf<<<128, BLK, 0, stream>>>(hp);
  // node 4: epilogue (16 blocks x 4 waves) + gen bump
  kp_epi<<<hp.B, BLK, 0, stream>>>(hp);
  (void)n_in; (void)out_size;
}

// Round 14
// 59.815 us; speedup vs baseline: 1.3192x; 1.3192x over previous
//
#include <hip/hip_runtime.h>

#define F 64
#define SECAP 8192
#define TCAP 2048
#define FCAP 8256
#define BLK 256
#define EPIW 4    // waves per kp_epi block
#define ZCAP 192  // LDS-cached zf rows per epi block (ten ~ 17 expected)

struct Params {
  const float *x, *ew, *f0w, *f0b, *f1w, *f1b, *cw, *cb;
  const int *pos, *esrc, *edst;
  float *out;
  int B, E;
  int *cnt;            // [0]=SE count, [2]=frontier count
  int *TEn;            // per-output-slot TE counts (B)
  unsigned *bitmap;    // frontier membership, (N+31)/32 words
  int *sel, *slotb, *slot_of, *SEb, *SEd, *TEsrc2;
  float *SEw, *TEw2, *AGG, *wsum;
  float *P0, *G, *V, *Wp;          // 64x64 weight products (kp_pre)
  float *b0c, *gb, *vb, *wpb;      // 64-vec products (kp_pre)
  int4 *zbase;                     // zero region base (cnt..bitmap contiguous)
  int nzvec;
};

// broadcast matvec: res = init + sum_f vec[f]*mat[f*64+h].
// vec may be LDS or global (uniform-address broadcast either way).
#define MVB(res, init, vecp, mat)                         \
  {                                                       \
    float a0_ = 0.f, a1_ = 0.f, a2_ = 0.f, a3_ = 0.f;     \
    _Pragma("unroll")                                     \
    for (int q_ = 0; q_ < 16; ++q_) {                     \
      float4 vv_ = ((const float4*)(vecp))[q_];           \
      a0_ += vv_.x * (mat)[(4 * q_ + 0) * 64 + h];        \
      a1_ += vv_.y * (mat)[(4 * q_ + 1) * 64 + h];        \
      a2_ += vv_.z * (mat)[(4 * q_ + 2) * 64 + h];        \
      a3_ += vv_.w * (mat)[(4 * q_ + 3) * 64 + h];        \
    }                                                     \
    res = (init) + ((a0_ + a1_) + (a2_ + a3_));           \
  }

// ---- K0: blocks 0-1: zero {cnt,TEn,bitmap} (~2 KB). blocks 2-5: 64x64
// ---- weight products. block 6: vector products. ----
__global__ __launch_bounds__(BLK) void kp_pre(Params p) {
  const int tid = threadIdx.x;
  const int bid = blockIdx.x;
  if (bid < 2) {
    for (int i = bid * BLK + tid; i < p.nzvec; i += 2 * BLK)
      p.zbase[i] = make_int4(0, 0, 0, 0);
    return;
  }
  __shared__ __align__(16) float Al[64][64];
  const int ty = tid >> 6, h = tid & 63;
  if (bid < 6) {
    int wb = bid - 2;
    const float *A, *A2 = nullptr, *Bm;
    float* Om;
    if (wb == 0)      { A = p.f0w;        Bm = p.cw;        Om = p.P0; }
    else if (wb == 1) { A = p.f1w;        A2 = p.f0w; Bm = p.cw; Om = p.G; }
    else if (wb == 2) { A = p.f1w + 4096; Bm = p.cw + 4096; Om = p.V; }
    else              { A = p.f0w + 4096; Bm = p.cw + 4096; Om = p.Wp; }
    for (int i = tid; i < 4096; i += BLK)
      Al[i >> 6][i & 63] = A2 ? (A[i] - A2[i]) : A[i];
    __syncthreads();
    float acc[16];
#pragma unroll
    for (int fi = 0; fi < 16; ++fi) acc[fi] = 0.f;
    for (int k = 0; k < 64; ++k) {
      float bkh = Bm[k * 64 + h];
#pragma unroll
      for (int fi = 0; fi < 16; ++fi)
        acc[fi] += Al[ty * 16 + fi][k] * bkh;
    }
#pragma unroll
    for (int fi = 0; fi < 16; ++fi)
      Om[(ty * 16 + fi) * 64 + h] = acc[fi];
  } else {
    const float *vsrc, *v2 = nullptr, *Bm;
    float* Ov;
    if (ty == 0)      { vsrc = p.f0b;      Bm = p.cw;        Ov = p.b0c; }
    else if (ty == 1) { vsrc = p.f1b;      v2 = p.f0b; Bm = p.cw; Ov = p.gb; }
    else if (ty == 2) { vsrc = p.f1b + 64; Bm = p.cw + 4096; Ov = p.vb; }
    else              { vsrc = p.f0b + 64; Bm = p.cw + 4096; Ov = p.wpb; }
    Al[ty][h] = v2 ? (vsrc[h] - v2[h]) : vsrc[h];   // same-wave LDS RAW
    float acc;
    MVB(acc, 0.f, Al[ty], Bm);
    Ov[h] = acc;
  }
}

// mark node n; first marker assigns a compact slot and zeroes its AGG row+wsum
__device__ __forceinline__ void mark_assign(const Params& p, int n) {
  unsigned bit = 1u << (n & 31);
  unsigned old = atomicOr(&p.bitmap[n >> 5], bit);
  if (!(old & bit)) {
    int sl = atomicAdd(&p.cnt[2], 1);
    if (sl < FCAP) {
      p.slot_of[n] = sl;
      float4* row = (float4*)(p.AGG + (size_t)sl * F);
#pragma unroll
      for (int k = 0; k < 16; ++k) row[k] = make_float4(0.f, 0.f, 0.f, 0.f);
      p.wsum[sl] = 0.f;
    } else {
      p.slot_of[n] = 0;   // pathological overflow guard
    }
  }
}

// ---- K1: edge scan, 1 edge/thread. SE list, TE buckets, frontier. ----
__global__ __launch_bounds__(BLK) void kp_scan(Params p) {
  __shared__ int posL[16], rankL[16];
  const int tid = threadIdx.x;
  const int B = p.B;
  if (tid < B) {
    int v = p.pos[tid];
    int rank = 0;
    for (int j = 0; j < B; ++j) rank += (p.pos[j] < v);
    posL[tid] = v;
    rankL[tid] = rank;
  }
  __syncthreads();
  if (blockIdx.x == 0 && tid < B) {
    p.sel[rankL[tid]] = posL[tid];      // unique ascending (values distinct)
    p.slotb[tid] = rankL[tid ^ 1];      // batch = rank of partner node
    mark_assign(p, posL[tid]);          // seed frontier with labeled nodes
  }
  int gtid = blockIdx.x * BLK + tid;
  int nthr = gridDim.x * BLK;
  for (int e = gtid; e < p.E; e += nthr) {
    int s = p.esrc[e], d = p.edst[e];
    float w = p.ew[e];
    int bi = -1, ti = -1;
#pragma unroll
    for (int j = 0; j < 16; ++j) {
      if (j < B) {
        if (s == posL[j]) bi = rankL[j];
        if (d == posL[j]) ti = j;
      }
    }
    if (bi >= 0) {                      // src is labeled: SE entry
      int idx = atomicAdd(&p.cnt[0], 1);
      if (idx < SECAP) { p.SEb[idx] = bi; p.SEd[idx] = d; p.SEw[idx] = w; }
    }
    if (ti >= 0) {                      // dst is a target: bucket + mark src
      int idx = atomicAdd(&p.TEn[ti], 1);
      if (idx < TCAP) { p.TEsrc2[ti * TCAP + idx] = s; p.TEw2[ti * TCAP + idx] = w; }
      mark_assign(p, s);
    }
  }
}

// ---- K2: AGG_x[slot(d)] += w * x[src] over edges into frontier nodes ----
__global__ __launch_bounds__(BLK) void kp_agg(Params p) {
  int gtid = blockIdx.x * BLK + threadIdx.x;
  int nthr = gridDim.x * BLK;
  for (int e = gtid; e < p.E; e += nthr) {
    int d = p.edst[e];
    if (!((p.bitmap[d >> 5] >> (d & 31)) & 1u)) continue;
    int sl = p.slot_of[d];
    if ((unsigned)sl >= (unsigned)FCAP) continue;
    int s = p.esrc[e];
    float w = p.ew[e];
    const float4* xs = (const float4*)(p.x + (size_t)s * F);
    float* dst = p.AGG + (size_t)sl * F;
#pragma unroll
    for (int k = 0; k < 16; ++k) {
      float4 v = xs[k];
      atomicAdd(dst + 4 * k + 0, w * v.x);
      atomicAdd(dst + 4 * k + 1, w * v.y);
      atomicAdd(dst + 4 * k + 2, w * v.z);
      atomicAdd(dst + 4 * k + 3, w * v.w);
    }
    atomicAdd(&p.wsum[sl], w);
  }
}

// zf row for slot sl, computed on the fly: AGG[sl]@P0 + wsum[sl]*b0c + cb0
#define ZROW(res, sl)                                                     \
  MVB(res, p.wsum[sl] * p.b0c[h] + p.cb[h], (p.AGG + (size_t)(sl) * F), p.P0)

// ---- K3: epilogue with inline zf. One block (4 waves) per output slot.
// ---- Waves 1-3 fill zbuf (independent MVBs); wave 0 does zself/x11T.
__global__ __launch_bounds__(BLK) void kp_epi(Params p) {
  __shared__ float cL[FCAP];              // c_{b,slot} for this block's batch b
  __shared__ __align__(16) float zbuf[ZCAP][64];
  __shared__ __align__(16) float v0[EPIW][64];
  __shared__ __align__(16) float Sp[EPIW][64];
  __shared__ float wnsL[EPIW], wselL[EPIW];
  __shared__ int slL[TCAP];
  __shared__ float twL[TCAP];
  const int t = blockIdx.x;
  const int tid = threadIdx.x;
  const int h = tid & 63, wv = tid >> 6;
  const int b = p.slotb[t];
  const int seln = p.sel[b];              // labeled node of batch b
  const int Fn = min(p.cnt[2], FCAP);
  for (int i = tid; i < Fn; i += BLK) cL[i] = 0.f;
  __syncthreads();
  // c-row: SE entries of batch b landing on frontier nodes (LDS atomics)
  int sen = min(p.cnt[0], SECAP);
  for (int i = tid; i < sen; i += BLK) {
    if (p.SEb[i] == b) {
      int d = p.SEd[i];
      if ((p.bitmap[d >> 5] >> (d & 31)) & 1u) {
        int sl = p.slot_of[d];
        if ((unsigned)sl < (unsigned)FCAP) atomicAdd(&cL[sl], p.SEw[i]);
      }
    }
  }
  // stage TE bucket: slot (or -1 for labeled-src) + weight
  int ten = min(p.TEn[t], TCAP);
  for (int i = tid; i < ten; i += BLK) {
    int s = p.TEsrc2[t * TCAP + i];
    int sl;
    if (s == seln) sl = -1;
    else { sl = p.slot_of[s]; if ((unsigned)sl >= (unsigned)FCAP) sl = 0; }
    slL[i] = sl;
    twL[i] = p.TEw2[t * TCAP + i];
  }
  __syncthreads();
  // per-wave g0 = x[seln]@G + gb (1 MVB)
  v0[wv][h] = p.x[(size_t)seln * F + h];  // same-wave in-order LDS RAW
  float g0h;
  MVB(g0h, p.gb[h], v0[wv], p.G);
  int sslot = p.slot_of[seln];
  if ((unsigned)sslot >= (unsigned)FCAP) sslot = 0;
  float x11Th = 0.f;
  if (wv == 0) {
    // wave 0: zself -> h1self -> x11T (needed only by wave 0's final combine)
    float zs;
    ZROW(zs, sslot);
    float h1self = fmaxf(zs + cL[sslot] * g0h, 0.f);
    v0[0][h] = h1self;
    MVB(x11Th, p.vb[h], v0[0], p.V);
  } else {
    // waves 1-3: fill zbuf for TE entries (independent 1-MVB transforms)
    int zmax = min(ten, ZCAP);
    for (int i = wv - 1; i < zmax; i += EPIW - 1) {
      int sl = slL[i];
      if (sl < 0) continue;
      float z;
      ZROW(z, sl);
      zbuf[i][h] = z;
    }
  }
  __syncthreads();
  // wave-split TE edge loop: LDS zbuf + FMA per entry
  float S = 0.f, wns = 0.f, wsel = 0.f;
  for (int i = wv; i < ten; i += EPIW) {
    int sl = slL[i];
    float w = twL[i];
    if (sl < 0) { wsel += w; continue; }
    float zv;
    if (i < ZCAP) zv = zbuf[i][h];
    else ZROW(zv, sl);                  // overflow fallback (never in practice)
    float h1 = fmaxf(zv + cL[sl] * g0h, 0.f);
    S += w * h1;
    wns += w;
  }
  Sp[wv][h] = S;
  if (h == 0) { wnsL[wv] = wns; wselL[wv] = wsel; }
  __syncthreads();
  // wave 0: combine, out = S@Wp + wns*wpb + wsel*x11T + cb1 (1 MVB)
  if (wv == 0) {
    float Sh = Sp[0][h] + Sp[1][h] + Sp[2][h] + Sp[3][h];
    float wnsT = wnsL[0] + wnsL[1] + wnsL[2] + wnsL[3];
    float wselT = wselL[0] + wselL[1] + wselL[2] + wselL[3];
    v0[0][h] = Sh;
    float o;
    MVB(o, wnsT * p.wpb[h] + wselT * x11Th + p.cb[64 + h], v0[0], p.Wp);
    p.out[t * F + h] = o;
  }
}

extern "C" void kernel_launch(void* const* d_in, const int* in_sizes, int n_in,
                              void* d_out, int out_size, void* d_ws, size_t ws_size,
                              hipStream_t stream) {
  Params hp;
  hp.x = (const float*)d_in[0];
  hp.pos = (const int*)d_in[1];
  hp.esrc = (const int*)d_in[2];
  hp.edst = (const int*)d_in[3];
  hp.ew = (const float*)d_in[4];
  hp.f0w = (const float*)d_in[5];
  hp.f0b = (const float*)d_in[6];
  hp.f1w = (const float*)d_in[7];
  hp.f1b = (const float*)d_in[8];
  hp.cw = (const float*)d_in[9];
  hp.cb = (const float*)d_in[10];
  hp.out = (float*)d_out;
  const int N = in_sizes[0] / F;   // 10000
  hp.B = in_sizes[1];              // 16
  hp.E = in_sizes[2];              // 160000

  char* w = (char*)d_ws;
  size_t off = 0;
  auto take = [&](size_t nb) { size_t r = off; off += (nb + 255) & ~(size_t)255; return r; };
  // ---- zeroed by kp_pre blocks 0-1 (contiguous from 0): cnt, TEn, bitmap ----
  size_t o_cnt = take(256);
  size_t o_ten = take(256);
  size_t o_bitmap = take(((size_t)N + 31) / 32 * 4);
  size_t zero_end = off;
  // ---- not zeroed (lazily initialized / fully overwritten before read) ----
  size_t o_sel = take(256);
  size_t o_slotb = take(256);
  size_t o_slotof = take((size_t)N * 4);
  size_t o_seb = take(SECAP * 4);
  size_t o_sed = take(SECAP * 4);
  size_t o_sew = take(SECAP * 4);
  size_t o_tesrc = take((size_t)hp.B * TCAP * 4);
  size_t o_tew = take((size_t)hp.B * TCAP * 4);
  size_t o_agg = take((size_t)FCAP * F * 4);
  size_t o_wsum = take((size_t)FCAP * 4);
  size_t o_P0 = take(4096 * 4);
  size_t o_G = take(4096 * 4);
  size_t o_V = take(4096 * 4);
  size_t o_Wp = take(4096 * 4);
  size_t o_b0c = take(256);
  size_t o_gb = take(256);
  size_t o_vb = take(256);
  size_t o_wpb = take(256);
  (void)ws_size;                   // ~3.7 MB total; ws is far larger

  hp.cnt = (int*)(w + o_cnt);
  hp.TEn = (int*)(w + o_ten);
  hp.bitmap = (unsigned*)(w + o_bitmap);
  hp.sel = (int*)(w + o_sel);
  hp.slotb = (int*)(w + o_slotb);
  hp.slot_of = (int*)(w + o_slotof);
  hp.SEb = (int*)(w + o_seb);
  hp.SEd = (int*)(w + o_sed);
  hp.SEw = (float*)(w + o_sew);
  hp.TEsrc2 = (int*)(w + o_tesrc);
  hp.TEw2 = (float*)(w + o_tew);
  hp.AGG = (float*)(w + o_agg);
  hp.wsum = (float*)(w + o_wsum);
  hp.P0 = (float*)(w + o_P0);
  hp.G = (float*)(w + o_G);
  hp.V = (float*)(w + o_V);
  hp.Wp = (float*)(w + o_Wp);
  hp.b0c = (float*)(w + o_b0c);
  hp.gb = (float*)(w + o_gb);
  hp.vb = (float*)(w + o_vb);
  hp.wpb = (float*)(w + o_wpb);
  hp.zbase = (int4*)w;
  hp.nzvec = (int)(zero_end / 16);

  // node 1: zero {cnt,TEn,bitmap} + weight products
  kp_pre<<<7, BLK, 0, stream>>>(hp);
  // node 2: edge scan (1 edge/thread)
  int nbE = (hp.E + BLK - 1) / BLK;
  if (nbE > 2048) nbE = 2048;
  kp_scan<<<nbE, BLK, 0, stream>>>(hp);
  // node 3: frontier aggregation (1 edge/thread)
  kp_agg<<<nbE, BLK, 0, stream>>>(hp);
  // node 4: epilogue with inline zf (16 blocks x 4 waves)
  kp_epi<<<hp.B, BLK, 0, stream>>>(hp);
  (void)n_in; (void)out_size;
}

// Round 15
// 55.766 us; speedup vs baseline: 1.4150x; 1.0726x over previous
//
#include <hip/hip_runtime.h>

#define F 64
#define SECAP 8192
#define TCAP 2048
#define FCAP 8256
#define BLK 256
#define EPIW 4   // waves per kp_epi block

struct Params {
  const float *x, *ew, *f0w, *f0b, *f1w, *f1b, *cw, *cb;
  const int *pos, *esrc, *edst;
  float *out;
  int B, E;
  int *cnt;            // [0]=SE count, [2]=frontier count
  int *TEn;            // per-output-slot TE counts (B)
  unsigned *bitmap;    // frontier membership, (N+31)/32 words
  int *sel, *slotb, *slot_of, *SEb, *SEd, *TEsrc2;
  float *SEw, *TEw2, *AGG, *wsum, *zf;
};

// mark node n; first marker assigns a compact slot and zeroes its AGG row+wsum
__device__ __forceinline__ void mark_assign(const Params& p, int n) {
  unsigned bit = 1u << (n & 31);
  unsigned old = atomicOr(&p.bitmap[n >> 5], bit);
  if (!(old & bit)) {
    int sl = atomicAdd(&p.cnt[2], 1);
    if (sl < FCAP) {
      p.slot_of[n] = sl;
      float4* row = (float4*)(p.AGG + (size_t)sl * F);
#pragma unroll
      for (int k = 0; k < 16; ++k) row[k] = make_float4(0.f, 0.f, 0.f, 0.f);
      p.wsum[sl] = 0.f;
    } else {
      p.slot_of[n] = 0;   // pathological overflow guard
    }
  }
}

// ---- K1: edge scan. Each block self-computes the pos rank table. Produces
// ---- SE list, per-slot TE buckets, frontier bitmap + compact slots.
__global__ __launch_bounds__(BLK) void kp_scan(Params p) {
  __shared__ int posL[16], rankL[16];
  const int tid = threadIdx.x;
  const int B = p.B;
  if (tid < B) {
    int v = p.pos[tid];
    int rank = 0;
    for (int j = 0; j < B; ++j) rank += (p.pos[j] < v);
    posL[tid] = v;
    rankL[tid] = rank;
  }
  __syncthreads();
  if (blockIdx.x == 0 && tid < B) {
    p.sel[rankL[tid]] = posL[tid];      // unique ascending (values distinct)
    p.slotb[tid] = rankL[tid ^ 1];      // batch = rank of partner node
    mark_assign(p, posL[tid]);          // seed frontier with labeled nodes
  }
  int gtid = blockIdx.x * BLK + tid;
  int nthr = gridDim.x * BLK;
  for (int e = gtid; e < p.E; e += nthr) {
    int s = p.esrc[e], d = p.edst[e];
    float w = p.ew[e];
    int bi = -1, ti = -1;
#pragma unroll
    for (int j = 0; j < 16; ++j) {
      if (j < B) {
        if (s == posL[j]) bi = rankL[j];
        if (d == posL[j]) ti = j;
      }
    }
    if (bi >= 0) {                      // src is labeled: SE entry
      int idx = atomicAdd(&p.cnt[0], 1);
      if (idx < SECAP) { p.SEb[idx] = bi; p.SEd[idx] = d; p.SEw[idx] = w; }
    }
    if (ti >= 0) {                      // dst is a target: bucket + mark src
      int idx = atomicAdd(&p.TEn[ti], 1);
      if (idx < TCAP) { p.TEsrc2[ti * TCAP + idx] = s; p.TEw2[ti * TCAP + idx] = w; }
      mark_assign(p, s);
    }
  }
}

// ---- K2: AGG_x[slot(d)] += w * x[src] over edges into frontier nodes ----
__global__ __launch_bounds__(BLK) void kp_agg(Params p) {
  int gtid = blockIdx.x * BLK + threadIdx.x;
  int nthr = gridDim.x * BLK;
  for (int e = gtid; e < p.E; e += nthr) {
    int d = p.edst[e];
    if (!((p.bitmap[d >> 5] >> (d & 31)) & 1u)) continue;
    int sl = p.slot_of[d];
    if ((unsigned)sl >= (unsigned)FCAP) continue;
    int s = p.esrc[e];
    float w = p.ew[e];
    const float4* xs = (const float4*)(p.x + (size_t)s * F);
    float* dst = p.AGG + (size_t)sl * F;
#pragma unroll
    for (int k = 0; k < 16; ++k) {
      float4 v = xs[k];
      atomicAdd(dst + 4 * k + 0, w * v.x);
      atomicAdd(dst + 4 * k + 1, w * v.y);
      atomicAdd(dst + 4 * k + 2, w * v.z);
      atomicAdd(dst + 4 * k + 3, w * v.w);
    }
    atomicAdd(&p.wsum[sl], w);
  }
}

// broadcast matvec: res = init + sum_f vec[f]*mat[f*64+h].
// vec is an LDS float[64] read as float4 broadcasts (16 ds_read_b128).
#define MVB(res, init, vecp, mat)                         \
  {                                                       \
    float a0_ = 0.f, a1_ = 0.f, a2_ = 0.f, a3_ = 0.f;     \
    _Pragma("unroll")                                     \
    for (int q_ = 0; q_ < 16; ++q_) {                     \
      float4 vv_ = ((const float4*)(vecp))[q_];           \
      a0_ += vv_.x * (mat)[(4 * q_ + 0) * 64 + h];        \
      a1_ += vv_.y * (mat)[(4 * q_ + 1) * 64 + h];        \
      a2_ += vv_.z * (mat)[(4 * q_ + 2) * 64 + h];        \
      a3_ += vv_.w * (mat)[(4 * q_ + 3) * 64 + h];        \
    }                                                     \
    res = (init) + ((a0_ + a1_) + (a2_ + a3_));           \
  }

// ---- K3: zf[slot] = (AGG_x@W0 + wsum*b0) @ cw0 + cb0, parallel over slots ----
__global__ __launch_bounds__(BLK) void kp_zf(Params p) {
  __shared__ __align__(16) float a[4][64], tt[4][64];
  const int Fn = min(p.cnt[2], FCAP);
  const int ty = threadIdx.x >> 6, h = threadIdx.x & 63;
  for (int sl = blockIdx.x * 4 + ty; sl < Fn; sl += gridDim.x * 4) {
    a[ty][h] = p.AGG[(size_t)sl * F + h];   // same-wave in-order LDS RAW
    float t1;
    MVB(t1, p.wsum[sl] * p.f0b[h], a[ty], p.f0w);
    tt[ty][h] = t1;
    float z;
    MVB(z, p.cb[h], tt[ty], p.cw);
    p.zf[(size_t)sl * F + h] = z;
  }
}

// ---- K4: epilogue. One block (4 waves) per output slot. TE loop is
// ---- zf-row loads + FMA (no matvecs in the loop).
__global__ __launch_bounds__(BLK) void kp_epi(Params p) {
  __shared__ float cL[FCAP];            // c_{b,slot} for this block's batch b
  __shared__ __align__(16) float v0[EPIW][64], v1[EPIW][64];
  __shared__ __align__(16) float Sp[EPIW][64];
  __shared__ float wnsL[EPIW], wselL[EPIW];
  __shared__ int slL[TCAP];
  __shared__ float twL[TCAP];
  const int t = blockIdx.x;
  const int tid = threadIdx.x;
  const int h = tid & 63, wv = tid >> 6;
  const int b = p.slotb[t];
  const int seln = p.sel[b];            // labeled node of batch b
  const int Fn = min(p.cnt[2], FCAP);
  for (int i = tid; i < Fn; i += BLK) cL[i] = 0.f;
  __syncthreads();
  // build c-row: SE entries of batch b landing on frontier nodes (LDS atomics)
  int sen = min(p.cnt[0], SECAP);
  for (int i = tid; i < sen; i += BLK) {
    if (p.SEb[i] == b) {
      int d = p.SEd[i];
      if ((p.bitmap[d >> 5] >> (d & 31)) & 1u) {
        int sl = p.slot_of[d];
        if ((unsigned)sl < (unsigned)FCAP) atomicAdd(&cL[sl], p.SEw[i]);
      }
    }
  }
  // stage TE bucket: slot (or -1 for labeled-src) + weight
  int ten = min(p.TEn[t], TCAP);
  for (int i = tid; i < ten; i += BLK) {
    int s = p.TEsrc2[t * TCAP + i];
    int sl;
    if (s == seln) sl = -1;
    else { sl = p.slot_of[s]; if ((unsigned)sl >= (unsigned)FCAP) sl = 0; }
    slL[i] = sl;
    twL[i] = p.TEw2[t * TCAP + i];
  }
  __syncthreads();
  // ---- per-wave (redundant, parallel): d0, g0, h1self, x11 ----
  v0[wv][h] = p.x[(size_t)seln * F + h];
  float d0h;
  {
    float a0_ = 0.f, a1_ = 0.f, a2_ = 0.f, a3_ = 0.f;
#pragma unroll
    for (int q = 0; q < 16; ++q) {
      float4 vv = ((const float4*)(v0[wv]))[q];
      a0_ += vv.x * (p.f1w[(4 * q + 0) * 64 + h] - p.f0w[(4 * q + 0) * 64 + h]);
      a1_ += vv.y * (p.f1w[(4 * q + 1) * 64 + h] - p.f0w[(4 * q + 1) * 64 + h]);
      a2_ += vv.z * (p.f1w[(4 * q + 2) * 64 + h] - p.f0w[(4 * q + 2) * 64 + h]);
      a3_ += vv.w * (p.f1w[(4 * q + 3) * 64 + h] - p.f0w[(4 * q + 3) * 64 + h]);
    }
    d0h = (p.f1b[h] - p.f0b[h]) + ((a0_ + a1_) + (a2_ + a3_));
  }
  v0[wv][h] = d0h;
  float g0h;
  MVB(g0h, 0.f, v0[wv], p.cw);
  // h1self = relu(zf[sslot] + c_self*g0); x11 = h1self @ f1w1 + f1b1
  int sslot = p.slot_of[seln];
  if ((unsigned)sslot >= (unsigned)FCAP) sslot = 0;
  float h1self = fmaxf(p.zf[(size_t)sslot * F + h] + cL[sslot] * g0h, 0.f);
  v0[wv][h] = h1self;
  float x11h;
  MVB(x11h, p.f1b[64 + h], v0[wv], (p.f1w + 4096));
  // ---- wave-split TE edge loop: one zf row load + FMA per entry ----
  float S = 0.f, wns = 0.f, wsel = 0.f;
  for (int i = wv; i < ten; i += EPIW) {
    int sl = slL[i];
    float w = twL[i];
    if (sl < 0) { wsel += w; continue; }
    float h1 = fmaxf(p.zf[(size_t)sl * F + h] + cL[sl] * g0h, 0.f);
    S += w * h1;
    wns += w;
  }
  Sp[wv][h] = S;
  if (h == 0) { wnsL[wv] = wns; wselL[wv] = wsel; }
  __syncthreads();
  // ---- wave 0: combine partials, final two matvecs, store ----
  if (wv == 0) {
    float Sh = Sp[0][h] + Sp[1][h] + Sp[2][h] + Sp[3][h];
    float wnsT = wnsL[0] + wnsL[1] + wnsL[2] + wnsL[3];
    float wselT = wselL[0] + wselL[1] + wselL[2] + wselL[3];
    v0[0][h] = Sh;
    float a2h;
    MVB(a2h, wnsT * p.f0b[64 + h] + wselT * x11h, v0[0], (p.f0w + 4096));
    v1[0][h] = a2h;
    float o;
    MVB(o, p.cb[64 + h], v1[0], (p.cw + 4096));
    p.out[t * F + h] = o;
  }
}

extern "C" void kernel_launch(void* const* d_in, const int* in_sizes, int n_in,
                              void* d_out, int out_size, void* d_ws, size_t ws_size,
                              hipStream_t stream) {
  Params hp;
  hp.x = (const float*)d_in[0];
  hp.pos = (const int*)d_in[1];
  hp.esrc = (const int*)d_in[2];
  hp.edst = (const int*)d_in[3];
  hp.ew = (const float*)d_in[4];
  hp.f0w = (const float*)d_in[5];
  hp.f0b = (const float*)d_in[6];
  hp.f1w = (const float*)d_in[7];
  hp.f1b = (const float*)d_in[8];
  hp.cw = (const float*)d_in[9];
  hp.cb = (const float*)d_in[10];
  hp.out = (float*)d_out;
  const int N = in_sizes[0] / F;   // 10000
  hp.B = in_sizes[1];              // 16
  hp.E = in_sizes[2];              // 160000

  char* w = (char*)d_ws;
  size_t off = 0;
  auto take = [&](size_t nb) { size_t r = off; off += (nb + 255) & ~(size_t)255; return r; };
  // ---- zeroed by ONE small memset (contiguous from 0): cnt, TEn, bitmap ----
  size_t o_cnt = take(256);
  size_t o_ten = take(256);
  size_t o_bitmap = take(((size_t)N + 31) / 32 * 4);
  size_t zero_end = off;
  // ---- not zeroed (lazily initialized / fully overwritten before read) ----
  size_t o_sel = take(256);
  size_t o_slotb = take(256);
  size_t o_slotof = take((size_t)N * 4);
  size_t o_seb = take(SECAP * 4);
  size_t o_sed = take(SECAP * 4);
  size_t o_sew = take(SECAP * 4);
  size_t o_tesrc = take((size_t)hp.B * TCAP * 4);
  size_t o_tew = take((size_t)hp.B * TCAP * 4);
  size_t o_agg = take((size_t)FCAP * F * 4);
  size_t o_wsum = take((size_t)FCAP * 4);
  size_t o_zf = take((size_t)FCAP * F * 4);
  (void)ws_size;                   // ~5.7 MB total; ws is far larger

  hp.cnt = (int*)(w + o_cnt);
  hp.TEn = (int*)(w + o_ten);
  hp.bitmap = (unsigned*)(w + o_bitmap);
  hp.sel = (int*)(w + o_sel);
  hp.slotb = (int*)(w + o_slotb);
  hp.slot_of = (int*)(w + o_slotof);
  hp.SEb = (int*)(w + o_seb);
  hp.SEd = (int*)(w + o_sed);
  hp.SEw = (float*)(w + o_sew);
  hp.TEsrc2 = (int*)(w + o_tesrc);
  hp.TEw2 = (float*)(w + o_tew);
  hp.AGG = (float*)(w + o_agg);
  hp.wsum = (float*)(w + o_wsum);
  hp.zf = (float*)(w + o_zf);

  // node 1: tiny memset (~2 KB)
  hipMemsetAsync(d_ws, 0, zero_end, stream);
  // node 2: edge scan
  int nbE = (hp.E + BLK - 1) / BLK;
  if (nbE > 2048) nbE = 2048;
  kp_scan<<<nbE, BLK, 0, stream>>>(hp);
  // node 3: frontier aggregation
  kp_agg<<<nbE, BLK, 0, stream>>>(hp);
  // node 4: zf transform, parallel over frontier slots
  kp_zf<<<256, BLK, 0, stream>>>(hp);
  // node 5: epilogue (16 blocks x 4 waves)
  kp_epi<<<hp.B, BLK, 0, stream>>>(hp);
  (void)n_in; (void)out_size;
}